// Round 13
// baseline (156.413 us; speedup 1.0000x reference)
//
#include <hip/hip_runtime.h>
#include <hip/hip_bf16.h>

#define NROWS 32768
#define HH 128
#define ENTN 50000

typedef _Float16 f16x8 __attribute__((ext_vector_type(8)));
typedef __fp16 fp16x2 __attribute__((ext_vector_type(2)));
typedef float f32x4 __attribute__((ext_vector_type(4)));

// ws byte offsets
#define OFF_EB  0                       // f16 [50000][128] (12.8 MB)
#define OFF_PEB 12800000                // u32 [50000][128] packed {f16 K*m | f16 K*g} per colpair (25.6 MB)
#define OFF_WF  38400000                // f16 [16jb][4kt][64][8] acc-weight frags, PRE-SCALED (65536 B)
#define OFF_PEF (OFF_WF + 65536)        // f16 [16jb][4kt][64][8] ent-weight frags, PRE-SCALED (65536 B)
#define OFF_POG (OFF_PEF + 65536)       // f32 [5][16jb][4lg][4i] op contrib, PRE-SCALED (5120 B)

#define KM 2.8853901f
#define KG (-1.4426950f)
#define RSTR 272                        // acc LDS row stride (256 + 16 pad)
#define PHALF (32 * RSTR)               // 8704 B per parity buffer

#if defined(__has_builtin)
#if __has_builtin(__builtin_amdgcn_exp2f)
#define FEXP2(x) __builtin_amdgcn_exp2f(x)
#endif
#endif
#ifndef FEXP2
__device__ __forceinline__ float __fexp2_asm(float x) {
    float r; asm("v_exp_f32 %0, %1" : "=v"(r) : "v"(x)); return r;
}
#define FEXP2(x) __fexp2_asm(x)
#endif

__device__ __forceinline__ unsigned pk2(float a, float b) {
    fp16x2 h = __builtin_amdgcn_cvt_pkrtz(a, b);
    unsigned u; __builtin_memcpy(&u, &h, 4); return u;
}
__device__ __forceinline__ float h2f(unsigned short s) {
    _Float16 h; __builtin_memcpy(&h, &s, 2); return (float)h;
}

// ---------------- prep: EB, WF/PEF/POG (all pre-scaled), out tail ----------------
__global__ void prep_kernel(const float* __restrict__ ent_table,
                            const float* __restrict__ op_table,
                            const float* __restrict__ non_table,
                            const float* __restrict__ Wm, const float* __restrict__ bm,
                            const float* __restrict__ Wg, const float* __restrict__ bg,
                            char* __restrict__ ws, float* __restrict__ out) {
    int idx = blockIdx.x * blockDim.x + threadIdx.x;
    if (idx < 800000) {                          // EB: ent_table -> f16, 8 elems/thread
        _Float16* EB = (_Float16*)(ws + OFF_EB);
        int base = idx * 8;
        const float4* s = (const float4*)(ent_table + base);
        float4 v0 = s[0], v1 = s[1];
        float xv[8] = {v0.x, v0.y, v0.z, v0.w, v1.x, v1.y, v1.z, v1.w};
        _Float16 h8[8];
        #pragma unroll
        for (int j = 0; j < 8; ++j) h8[j] = (_Float16)xv[j];
        *(f16x8*)(EB + base) = *(f16x8*)h8;
    } else if (idx < 832768) {                   // WF: acc-path frags, pre-scaled
        int e = idx - 800000;
        int jj = e & 7, l = (e >> 3) & 63, kt = (e >> 9) & 3, jb = e >> 11;
        int j = jb * 16 + (l & 15);
        int c = j >> 1, p = j & 1;
        int k = kt * 32 + (l >> 4) * 8 + jj;
        const float* Wrow = p ? (Wg + (size_t)c * 384) : (Wm + (size_t)c * 384);
        ((_Float16*)(ws + OFF_WF))[e] = (_Float16)(Wrow[256 + k] * (p ? KG : KM));
    } else if (idx < 865536) {                   // PEF: ent-path frags, pre-scaled
        int e = idx - 832768;
        int jj = e & 7, l = (e >> 3) & 63, kt = (e >> 9) & 3, jb = e >> 11;
        int j = jb * 16 + (l & 15);
        int c = j >> 1, p = j & 1;
        int k = kt * 32 + (l >> 4) * 8 + jj;
        const float* Wrow = p ? (Wg + (size_t)c * 384) : (Wm + (size_t)c * 384);
        ((_Float16*)(ws + OFF_PEF))[e] = (_Float16)(Wrow[128 + k] * (p ? KG : KM));
    } else if (idx < 866816) {                   // POG: op contrib + bias, pre-scaled
        int e = idx - 865536;
        int o = e >> 8, rem = e & 255;
        int jb = rem >> 4, lg = (rem >> 2) & 3, i = rem & 3;
        int j = jb * 16 + 4 * lg + i;
        int c = j >> 1, p = j & 1;
        const float* Wrow = p ? (Wg + (size_t)c * 384) : (Wm + (size_t)c * 384);
        float s = p ? bg[c] : bm[c];
        for (int k = 0; k < 128; ++k) s += op_table[o * HH + k] * Wrow[k];
        ((float*)(ws + OFF_POG))[e] = s * (p ? KG : KM);
    } else if (idx < 866944) {
        int j = idx - 866816;
        out[(size_t)NROWS * HH + j] = non_table[j];
    }
}

// ---------------- PEB = pack(pre-scaled W_ent @ EB^T), transposed MFMA, f16 source ----------------
__global__ __launch_bounds__(1024, 2)
void pe_kernel(char* __restrict__ ws) {
    const char* EBc = ws + OFF_EB;
    const f16x8* PEF = (const f16x8*)(ws + OFF_PEF);
    unsigned* PEB = (unsigned*)(ws + OFF_PEB);
    int tid = threadIdx.x, jb = tid >> 6, l = tid & 63, lr = l & 15, lg = (l >> 4) & 3;
    int e0 = blockIdx.x * 32;
    int c1 = jb * 8 + 2 * lg;

    f16x8 WB[4];
    #pragma unroll
    for (int kt = 0; kt < 4; ++kt) WB[kt] = PEF[(jb * 4 + kt) * 64 + l];

    f32x4 C[2];
    C[0] = (f32x4){0.f, 0.f, 0.f, 0.f};
    C[1] = (f32x4){0.f, 0.f, 0.f, 0.f};

    #pragma unroll
    for (int kt = 0; kt < 4; ++kt) {
        #pragma unroll
        for (int rt = 0; rt < 2; ++rt) {
            int e = e0 + rt * 16 + lr;
            if (e >= ENTN) e = ENTN - 1;
            f16x8 A = *(const f16x8*)(EBc + (size_t)e * 256 + kt * 64 + lg * 16);
            C[rt] = __builtin_amdgcn_mfma_f32_16x16x32_f16(WB[kt], A, C[rt], 0, 0, 0);
        }
    }
    #pragma unroll
    for (int rt = 0; rt < 2; ++rt) {
        int e = e0 + rt * 16 + lr;
        if (e < ENTN) {
            uint2 st;
            st.x = pk2(C[rt][0], C[rt][1]);
            st.y = pk2(C[rt][2], C[rt][3]);
            *(uint2*)(PEB + (size_t)e * HH + c1) = st;
        }
    }
}

// ---------------- fused 17-step chain: 8 waves x 2jb, 32 rows, prefetch 1 ahead ----------------
__global__ __launch_bounds__(512, 4)
void chain_kernel(const float* __restrict__ ent_table,
                  const int* __restrict__ ops_idx,
                  const int* __restrict__ ents_idx,
                  const int* __restrict__ left_idx,
                  const char* __restrict__ ws, float* __restrict__ out) {
    __shared__ char Abuf[2 * PHALF];   // [2p][32r][272B]
    __shared__ unsigned eo[32 * 17];   // (e<<3) | o, [r][t]

    const char* PEBc = ws + OFF_PEB;
    const f16x8* WFp = (const f16x8*)(ws + OFF_WF);
    const char* POGc = ws + OFF_POG;

    int tid = threadIdx.x;
    int w = tid >> 6, l = tid & 63, lr = l & 15, lg = (l >> 4) & 3;
    int row0 = blockIdx.x * 32;
    int jb0 = 2 * w;

    for (int i = tid; i < 544; i += 512) {
        int r = i / 17, t = i - r * 17;
        unsigned e, o;
        if (t < 16) {
            e = ents_idx[(row0 + r) * 17 + 15 - t];
            o = ops_idx[(row0 + r) * 16 + 15 - t];
        } else {
            e = left_idx[row0 + r];
            o = 4;
        }
        eo[i] = (e << 3) | o;
    }

    // pre-scaled acc-weight frags for this wave's two jb slices
    f16x8 WH0[4], WH1[4];
    #pragma unroll
    for (int kt = 0; kt < 4; ++kt) {
        WH0[kt] = WFp[(jb0 * 4 + kt) * 64 + l];
        WH1[kt] = WFp[((jb0 + 1) * 4 + kt) * 64 + l];
    }

    {   // acc0 init -> parity 0
        int r = tid >> 4, sub = tid & 15;
        int e = ents_idx[(row0 + r) * 17 + 16];
        const float4* src = (const float4*)(ent_table + (size_t)e * HH + sub * 8);
        float4 v0 = src[0], v1 = src[1];
        uint4 d;
        d.x = pk2(v0.x, v0.y); d.y = pk2(v0.z, v0.w);
        d.z = pk2(v1.x, v1.y); d.w = pk2(v1.z, v1.w);
        *(uint4*)(Abuf + r * RSTR + sub * 16) = d;
    }
    __syncthreads();

    int rb = lr * RSTR + lg * 16;                 // acc read base
    int wb = lr * RSTR + jb0 * 16 + lg * 4;       // acc write base (jb1 at +16)
    const unsigned* eoB0 = eo + lr * 17;
    const unsigned* eoB1 = eo + (16 + lr) * 17;
    const char* pebL = PEBc + jb0 * 32 + lg * 8;  // + e*512 (+32 for jb1)
    const char* pogL = POGc + w * 128 + lg * 16;  // + o*1024 (+64 for jb1)

    // current-step prefetch state
    uint2 pec[4];     // [rt*2 + jbi]
    f32x4 poc[4];
    {
        unsigned va = eoB0[0], vb = eoB1[0];
        const char* pa = pebL + (size_t)(va >> 3) * 512;
        const char* pb = pebL + (size_t)(vb >> 3) * 512;
        pec[0] = *(const uint2*)(pa);      pec[1] = *(const uint2*)(pa + 32);
        pec[2] = *(const uint2*)(pb);      pec[3] = *(const uint2*)(pb + 32);
        const char* qa = pogL + (va & 7u) * 1024;
        const char* qb = pogL + (vb & 7u) * 1024;
        poc[0] = *(const f32x4*)(qa);      poc[1] = *(const f32x4*)(qa + 64);
        poc[2] = *(const f32x4*)(qb);      poc[3] = *(const f32x4*)(qb + 64);
    }

#define ACT_STORE(Z, PE, RT, JBI, WR, FINAL)                                    \
    {                                                                           \
        f32x4 a = (Z);                                                          \
        a[0] += h2f((unsigned short)(PE).x);                                    \
        a[1] += h2f((unsigned short)((PE).x >> 16));                            \
        a[2] += h2f((unsigned short)(PE).y);                                    \
        a[3] += h2f((unsigned short)((PE).y >> 16));                            \
        f32x4 ev;                                                               \
        ev[0] = FEXP2(a[0]); ev[1] = FEXP2(a[1]);                               \
        ev[2] = FEXP2(a[2]); ev[3] = FEXP2(a[3]);                               \
        f32x4 p1 = ev + 1.0f;                                                   \
        float r1 = (ev[0] - 1.f) * __builtin_amdgcn_rcpf(p1[0] * p1[1]);        \
        float r2 = (ev[2] - 1.f) * __builtin_amdgcn_rcpf(p1[2] * p1[3]);        \
        if (FINAL) {                                                            \
            *(float2*)(out + (size_t)(row0 + (RT) * 16 + lr) * HH               \
                       + (jb0 + (JBI)) * 8 + 2 * lg) = make_float2(r1, r2);     \
        } else {                                                                \
            *(unsigned*)(Abuf + wb + (WR) + (RT) * 16 * RSTR + (JBI) * 16)      \
                = pk2(r1, r2);                                                  \
        }                                                                       \
    }

#define DO_STEP(T, RD, WR, FINAL)                                               \
    {                                                                           \
        f32x4 C00 = poc[0], C01 = poc[1], C10 = poc[2], C11 = poc[3];           \
        uint2 pen[4]; f32x4 pon[4];                                             \
        if (!(FINAL)) {                 /* prefetch for T+1 */                   \
            unsigned va = eoB0[(T) + 1], vb = eoB1[(T) + 1];                    \
            const char* pa = pebL + (size_t)(va >> 3) * 512;                    \
            const char* pb = pebL + (size_t)(vb >> 3) * 512;                    \
            pen[0] = *(const uint2*)(pa);  pen[1] = *(const uint2*)(pa + 32);   \
            pen[2] = *(const uint2*)(pb);  pen[3] = *(const uint2*)(pb + 32);   \
            const char* qa = pogL + (va & 7u) * 1024;                           \
            const char* qb = pogL + (vb & 7u) * 1024;                           \
            pon[0] = *(const f32x4*)(qa);  pon[1] = *(const f32x4*)(qa + 64);   \
            pon[2] = *(const f32x4*)(qb);  pon[3] = *(const f32x4*)(qb + 64);   \
        }                                                                       \
        _Pragma("unroll")                                                       \
        for (int kt = 0; kt < 4; ++kt) {                                        \
            f16x8 A0 = *(const f16x8*)(Abuf + rb + (RD) + kt * 64);             \
            f16x8 A1 = *(const f16x8*)(Abuf + rb + (RD) + 16 * RSTR + kt * 64); \
            C00 = __builtin_amdgcn_mfma_f32_16x16x32_f16(WH0[kt], A0, C00, 0, 0, 0); \
            C01 = __builtin_amdgcn_mfma_f32_16x16x32_f16(WH1[kt], A0, C01, 0, 0, 0); \
            C10 = __builtin_amdgcn_mfma_f32_16x16x32_f16(WH0[kt], A1, C10, 0, 0, 0); \
            C11 = __builtin_amdgcn_mfma_f32_16x16x32_f16(WH1[kt], A1, C11, 0, 0, 0); \
        }                                                                       \
        ACT_STORE(C00, pec[0], 0, 0, WR, FINAL)                                 \
        ACT_STORE(C01, pec[1], 0, 1, WR, FINAL)                                 \
        ACT_STORE(C10, pec[2], 1, 0, WR, FINAL)                                 \
        ACT_STORE(C11, pec[3], 1, 1, WR, FINAL)                                 \
        __syncthreads();                                                        \
        if (!(FINAL)) {                                                         \
            pec[0] = pen[0]; pec[1] = pen[1]; pec[2] = pen[2]; pec[3] = pen[3]; \
            poc[0] = pon[0]; poc[1] = pon[1]; poc[2] = pon[2]; poc[3] = pon[3]; \
        }                                                                       \
    }

    for (int tb = 0; tb < 8; ++tb) {
        int t0 = 2 * tb;
        DO_STEP(t0, 0, PHALF, 0)
        DO_STEP(t0 + 1, PHALF, 0, 0)
    }
    DO_STEP(16, 0, PHALF, 1)
#undef DO_STEP
#undef ACT_STORE
}

extern "C" void kernel_launch(void* const* d_in, const int* in_sizes, int n_in,
                              void* d_out, int out_size, void* d_ws, size_t ws_size,
                              hipStream_t stream) {
    const float* ent_table = (const float*)d_in[0];
    const float* op_table  = (const float*)d_in[1];
    const float* non_table = (const float*)d_in[2];
    const float* Wm        = (const float*)d_in[3];
    const float* bm        = (const float*)d_in[4];
    const float* Wg        = (const float*)d_in[5];
    const float* bg        = (const float*)d_in[6];
    const int* ops_idx     = (const int*)d_in[7];
    const int* ents_idx    = (const int*)d_in[8];
    const int* left_idx    = (const int*)d_in[9];
    float* out = (float*)d_out;
    char* ws = (char*)d_ws;

    prep_kernel<<<3387, 256, 0, stream>>>(ent_table, op_table, non_table,
                                          Wm, bm, Wg, bg, ws, out);
    pe_kernel<<<1563, 1024, 0, stream>>>(ws);
    chain_kernel<<<NROWS / 32, 512, 0, stream>>>(ent_table, ops_idx, ents_idx,
                                                 left_idx, ws, out);
}

// Round 14
// 106.995 us; speedup vs baseline: 1.4619x; 1.4619x over previous
//
#include <hip/hip_runtime.h>
#include <hip/hip_bf16.h>

#define NROWS 32768
#define HH 128
#define ENTN 50000

typedef _Float16 f16x8 __attribute__((ext_vector_type(8)));
typedef __fp16 fp16x2 __attribute__((ext_vector_type(2)));
typedef float f32x4 __attribute__((ext_vector_type(4)));

// ws byte offsets
#define OFF_PEB 0                       // u32 [50000][128] packed {f16 K*m | f16 K*g} per colpair (25.6 MB)
#define OFF_EB  25600000                // f16 [50000][128] (12.8 MB)
#define OFF_WF  38400000                // f16 [16jb][4kt][64][8] acc-weight frags, j-interleaved, raw
#define OFF_PEF (OFF_WF + 65536)        // f16 [16jb][4kt][64][8] ent-weight frags, j-interleaved, raw
#define OFF_PO  (OFF_PEF + 65536)       // f32 [5][260] {m,g,m,g} per colpair, PRE-SCALED

#define KM 2.8853901f
#define KG (-1.4426950f)
#define RSTR 272                        // acc LDS row stride (256 + 16 pad)
#define HALF (32 * RSTR)

#if defined(__has_builtin)
#if __has_builtin(__builtin_amdgcn_exp2f)
#define FEXP2(x) __builtin_amdgcn_exp2f(x)
#endif
#endif
#ifndef FEXP2
__device__ __forceinline__ float __fexp2_asm(float x) {
    float r; asm("v_exp_f32 %0, %1" : "=v"(r) : "v"(x)); return r;
}
#define FEXP2(x) __fexp2_asm(x)
#endif

__device__ __forceinline__ unsigned pk2(float a, float b) {
    fp16x2 h = __builtin_amdgcn_cvt_pkrtz(a, b);
    unsigned u; __builtin_memcpy(&u, &h, 4); return u;
}
__device__ __forceinline__ float h2f(unsigned short s) {
    _Float16 h; __builtin_memcpy(&h, &s, 2); return (float)h;
}

// ---------------- prep: EB, WF, PEF, PO(pre-scaled), out tail ----------------
__global__ void prep_kernel(const float* __restrict__ ent_table,
                            const float* __restrict__ op_table,
                            const float* __restrict__ non_table,
                            const float* __restrict__ Wm, const float* __restrict__ bm,
                            const float* __restrict__ Wg, const float* __restrict__ bg,
                            char* __restrict__ ws, float* __restrict__ out) {
    int idx = blockIdx.x * blockDim.x + threadIdx.x;
    if (idx < 800000) {                          // EB: ent_table -> f16, 8 elems/thread
        _Float16* EB = (_Float16*)(ws + OFF_EB);
        int base = idx * 8;
        const float4* s = (const float4*)(ent_table + base);
        float4 v0 = s[0], v1 = s[1];
        float xv[8] = {v0.x, v0.y, v0.z, v0.w, v1.x, v1.y, v1.z, v1.w};
        _Float16 h8[8];
        #pragma unroll
        for (int j = 0; j < 8; ++j) h8[j] = (_Float16)xv[j];
        *(f16x8*)(EB + base) = *(f16x8*)h8;
    } else if (idx < 832768) {                   // WF: acc-path frags (raw)
        int e = idx - 800000;
        int jj = e & 7, l = (e >> 3) & 63, kt = (e >> 9) & 3, jb = e >> 11;
        int j = jb * 16 + (l & 15);
        int c = j >> 1, p = j & 1;
        int k = kt * 32 + (l >> 4) * 8 + jj;
        const float* Wrow = p ? (Wg + (size_t)c * 384) : (Wm + (size_t)c * 384);
        ((_Float16*)(ws + OFF_WF))[e] = (_Float16)Wrow[256 + k];
    } else if (idx < 865536) {                   // PEF: ent-path frags (raw)
        int e = idx - 832768;
        int jj = e & 7, l = (e >> 3) & 63, kt = (e >> 9) & 3, jb = e >> 11;
        int j = jb * 16 + (l & 15);
        int c = j >> 1, p = j & 1;
        int k = kt * 32 + (l >> 4) * 8 + jj;
        const float* Wrow = p ? (Wg + (size_t)c * 384) : (Wm + (size_t)c * 384);
        ((_Float16*)(ws + OFF_PEF))[e] = (_Float16)Wrow[128 + k];
    } else if (idx < 866816) {                   // PO: pre-scaled, colpair-interleaved
        int e = idx - 865536;
        int o = e >> 8, jj = e & 255;
        int c = jj >> 1, p = jj & 1;
        const float* Wrow = p ? (Wg + (size_t)c * 384) : (Wm + (size_t)c * 384);
        float s = p ? bg[c] : bm[c];
        for (int i = 0; i < 128; ++i) s += op_table[o * HH + i] * Wrow[i];
        s *= (p ? KG : KM);
        ((float*)(ws + OFF_PO))[o * 260 + (c >> 1) * 4 + 2 * (c & 1) + p] = s;
    } else if (idx < 866944) {
        int j = idx - 866816;
        out[(size_t)NROWS * HH + j] = non_table[j];
    }
}

// ---------------- PEB = pack(K * (W_ent @ EB^T)): 256-thr, A reused across 4 jb ----------------
__global__ __launch_bounds__(256, 4)
void pe_kernel(char* __restrict__ ws) {
    const char* EBc = ws + OFF_EB;
    const f16x8* PEF = (const f16x8*)(ws + OFF_PEF);
    unsigned* PEB = (unsigned*)(ws + OFF_PEB);
    int tid = threadIdx.x, w = tid >> 6, l = tid & 63, lr = l & 15, lg = (l >> 4) & 3;
    int e0 = blockIdx.x * 32;

    f16x8 WB[4][4];
    #pragma unroll
    for (int u = 0; u < 4; ++u)
        #pragma unroll
        for (int kt = 0; kt < 4; ++kt)
            WB[u][kt] = PEF[((4 * w + u) * 4 + kt) * 64 + l];

    f32x4 C[2][4];
    #pragma unroll
    for (int rt = 0; rt < 2; ++rt)
        #pragma unroll
        for (int u = 0; u < 4; ++u) C[rt][u] = (f32x4){0.f, 0.f, 0.f, 0.f};

    #pragma unroll
    for (int kt = 0; kt < 4; ++kt) {
        #pragma unroll
        for (int rt = 0; rt < 2; ++rt) {
            int e = e0 + rt * 16 + lr;
            if (e >= ENTN) e = ENTN - 1;
            f16x8 A = *(const f16x8*)(EBc + (size_t)e * 256 + kt * 64 + lg * 16);
            #pragma unroll
            for (int u = 0; u < 4; ++u)
                C[rt][u] = __builtin_amdgcn_mfma_f32_16x16x32_f16(WB[u][kt], A, C[rt][u], 0, 0, 0);
        }
    }
    #pragma unroll
    for (int rt = 0; rt < 2; ++rt) {
        int e = e0 + rt * 16 + lr;
        if (e < ENTN) {
            #pragma unroll
            for (int u = 0; u < 4; ++u) {
                uint2 st;
                st.x = pk2(C[rt][u][0] * KM, C[rt][u][1] * KG);
                st.y = pk2(C[rt][u][2] * KM, C[rt][u][3] * KG);
                *(uint2*)(PEB + (size_t)e * HH + (4 * w + u) * 8 + 2 * lg) = st;
            }
        }
    }
}

// ---------------- fused 17-step chain (v11 verbatim): prefetch 1 ahead, raw exp2 ----------------
__global__ __launch_bounds__(1024, 8)
void chain_kernel(const float* __restrict__ ent_table,
                  const int* __restrict__ ops_idx,
                  const int* __restrict__ ents_idx,
                  const int* __restrict__ left_idx,
                  const char* __restrict__ ws, float* __restrict__ out) {
    __shared__ char Abuf[2 * HALF];    // [2p][32r][272B]
    __shared__ unsigned eo[32 * 17];   // (e<<9) | o, [r][t]
    __shared__ float po_s[5 * 260];

    const char* PEBc = ws + OFF_PEB;
    const f16x8* WF2p = (const f16x8*)(ws + OFF_WF);
    const float* POg = (const float*)(ws + OFF_PO);

    int tid = threadIdx.x;
    int jb = tid >> 6, l = tid & 63, lr = l & 15, lg = (l >> 4) & 3;
    int row0 = blockIdx.x * 32;
    int c1 = jb * 8 + 2 * lg;

    if (tid < 544) {
        int r = tid / 17, t = tid - r * 17;
        unsigned e, o;
        if (t < 16) {
            e = ents_idx[(row0 + r) * 17 + 15 - t];
            o = ops_idx[(row0 + r) * 16 + 15 - t];
        } else {
            e = left_idx[row0 + r];
            o = 4;
        }
        eo[tid] = (e << 9) | o;
    }
    for (int i = tid; i < 1300; i += 1024) po_s[i] = POg[i];

    f16x8 WH[4];
    #pragma unroll
    for (int kt = 0; kt < 4; ++kt)
        WH[kt] = WF2p[(jb * 4 + kt) * 64 + l];

    {   // acc0 init -> parity 0
        int r = tid >> 5, sub = tid & 31;
        int e = ents_idx[(row0 + r) * 17 + 16];
        float4 v = *(const float4*)(ent_table + (size_t)e * HH + sub * 4);
        uint2 d;
        d.x = pk2(v.x, v.y);
        d.y = pk2(v.z, v.w);
        *(uint2*)(Abuf + r * RSTR + sub * 8) = d;
    }
    __syncthreads();

    int rb = lr * RSTR + lg * 16;            // MFMA B-operand read base
    int wb = lr * RSTR + jb * 16 + 4 * lg;   // acc write base
    const char* pebBase = PEBc + c1 * 4;
    const float* poBase = po_s + (4 * jb + lg) * 4;
    const unsigned* eoB = eo + lr * 17;

    const f32x4 K4 = (f32x4){KM, KG, KM, KG};

    // prologue: gather for t=0
    unsigned va = eoB[0], vb = eoB[272];
    uint2 pea = *(const uint2*)(pebBase + (va & 0xFFFFFE00u));
    uint2 peb = *(const uint2*)(pebBase + (vb & 0xFFFFFE00u));

#define DO_STEP(T, RD, WR, FINAL)                                               \
    {                                                                           \
        uint2 npea, npeb; unsigned nva = 0, nvb = 0;                            \
        if (!(FINAL)) {                                                         \
            nva = eoB[(T) + 1];                                                 \
            nvb = eoB[272 + (T) + 1];                                           \
            npea = *(const uint2*)(pebBase + (nva & 0xFFFFFE00u));              \
            npeb = *(const uint2*)(pebBase + (nvb & 0xFFFFFE00u));              \
        }                                                                       \
        f32x4 poa = *(const f32x4*)(poBase + (va & 7u) * 260);                  \
        f32x4 pob = *(const f32x4*)(poBase + (vb & 7u) * 260);                  \
        f32x4 C0 = (f32x4){0.f, 0.f, 0.f, 0.f};                                 \
        f32x4 C1 = (f32x4){0.f, 0.f, 0.f, 0.f};                                 \
        _Pragma("unroll")                                                       \
        for (int kt = 0; kt < 4; ++kt) {                                        \
            f16x8 A0 = *(const f16x8*)(Abuf + rb + (RD) + kt * 64);             \
            f16x8 A1 = *(const f16x8*)(Abuf + rb + (RD) + 16 * RSTR + kt * 64); \
            C0 = __builtin_amdgcn_mfma_f32_16x16x32_f16(WH[kt], A0, C0, 0, 0, 0); \
            C1 = __builtin_amdgcn_mfma_f32_16x16x32_f16(WH[kt], A1, C1, 0, 0, 0); \
        }                                                                       \
        _Pragma("unroll")                                                       \
        for (int rt = 0; rt < 2; ++rt) {                                        \
            uint2 pe = rt ? peb : pea;                                          \
            f32x4 po = rt ? pob : poa;                                          \
            f32x4 z = rt ? C1 : C0;                                             \
            f32x4 pef;                                                          \
            pef[0] = h2f((unsigned short)pe.x);                                 \
            pef[1] = h2f((unsigned short)(pe.x >> 16));                         \
            pef[2] = h2f((unsigned short)pe.y);                                 \
            pef[3] = h2f((unsigned short)(pe.y >> 16));                         \
            f32x4 s4 = pef + po;                                                \
            f32x4 a = z * K4 + s4;                                              \
            f32x4 ev;                                                           \
            ev[0] = FEXP2(a[0]); ev[1] = FEXP2(a[1]);                           \
            ev[2] = FEXP2(a[2]); ev[3] = FEXP2(a[3]);                           \
            f32x4 p1 = ev + 1.0f;                                               \
            float r1 = (ev[0] - 1.f) * __builtin_amdgcn_rcpf(p1[0] * p1[1]);    \
            float r2 = (ev[2] - 1.f) * __builtin_amdgcn_rcpf(p1[2] * p1[3]);    \
            if (FINAL) {                                                        \
                float2 o2 = make_float2(r1, r2);                                \
                *(float2*)(out + (size_t)(row0 + rt * 16 + lr) * HH + c1) = o2; \
            } else {                                                            \
                *(unsigned*)(Abuf + wb + (WR) + rt * 16 * RSTR) = pk2(r1, r2);  \
            }                                                                   \
        }                                                                       \
        __syncthreads();                                                        \
        if (!(FINAL)) { pea = npea; peb = npeb; va = nva; vb = nvb; }           \
    }

    for (int tb = 0; tb < 8; ++tb) {
        int t0 = 2 * tb;
        DO_STEP(t0, 0, HALF, 0)
        DO_STEP(t0 + 1, HALF, 0, 0)
    }
    DO_STEP(16, 0, HALF, 1)
#undef DO_STEP
}

extern "C" void kernel_launch(void* const* d_in, const int* in_sizes, int n_in,
                              void* d_out, int out_size, void* d_ws, size_t ws_size,
                              hipStream_t stream) {
    const float* ent_table = (const float*)d_in[0];
    const float* op_table  = (const float*)d_in[1];
    const float* non_table = (const float*)d_in[2];
    const float* Wm        = (const float*)d_in[3];
    const float* bm        = (const float*)d_in[4];
    const float* Wg        = (const float*)d_in[5];
    const float* bg        = (const float*)d_in[6];
    const int* ops_idx     = (const int*)d_in[7];
    const int* ents_idx    = (const int*)d_in[8];
    const int* left_idx    = (const int*)d_in[9];
    float* out = (float*)d_out;
    char* ws = (char*)d_ws;

    prep_kernel<<<3387, 256, 0, stream>>>(ent_table, op_table, non_table,
                                          Wm, bm, Wg, bg, ws, out);
    pe_kernel<<<1563, 256, 0, stream>>>(ws);
    chain_kernel<<<NROWS / 32, 1024, 0, stream>>>(ent_table, ops_idx, ents_idx,
                                                  left_idx, ws, out);
}